// Round 4
// baseline (366.334 us; speedup 1.0000x reference)
//
#include <hip/hip_runtime.h>
#include <hip/hip_bf16.h>

namespace {
constexpr int B = 4, N = 6, D = 41, FH = 16, FW = 44, C = 64;
constexpr int NX = 200, NY = 200;                 // NZ = 1
constexpr int NGROUPS = B * N * D * FW;           // 43296 ray-groups (all h)
constexpr long long ACC_ELEMS = (long long)B * NY * NX * C;  // 10,240,000
constexpr int PARAMS_PER_CAM = 24;                // iPR[9], pt[3], M[9], t[3]
constexpr int FLAG_IDX = B * N * PARAMS_PER_CAM;  // int flag at params[576]
// ws float-offsets: [0,ACC) acc | [ACC, ACC+577) params+flag |
// counter int at params[640] | segment list (int2) at params[704]
constexpr int CTR_OFF = 640;
constexpr int SEG_OFF = 704;
}

__device__ __forceinline__ float ldin(const void* p, size_t idx, int fp32m) {
  return fp32m ? ((const float*)p)[idx]
               : __bfloat162float(((const __hip_bfloat16*)p)[idx]);
}

// Strict fp32 left-fold 3-term dot (numpy einsum order, no FMA).
__device__ __forceinline__ float dot3(float m0, float m1, float m2, float a0,
                                      float a1, float a2) {
  return __fadd_rn(__fadd_rn(__fmul_rn(m0, a0), __fmul_rn(m1, a1)),
                   __fmul_rn(m2, a2));
}

// Per-(group,h) voxel id, or -1 if not kept. Bit-identical fp32 ops vs R2/R3.
__device__ __forceinline__ int voxel_of(const float* pr, float ax, float az,
                                        int b, int h) {
  float v = (float)(17 * h);  // linspace(0,255,16), exact
  float ay = __fsub_rn(v, pr[10]);
  float qx = dot3(pr[0], pr[1], pr[2], ax, ay, az);
  float qy = dot3(pr[3], pr[4], pr[5], ax, ay, az);
  float qz = dot3(pr[6], pr[7], pr[8], ax, ay, az);
  qx = __fmul_rn(qx, qz);
  qy = __fmul_rn(qy, qz);
  float gx = __fadd_rn(dot3(pr[12], pr[13], pr[14], qx, qy, qz), pr[21]);
  float gy = __fadd_rn(dot3(pr[15], pr[16], pr[17], qx, qy, qz), pr[22]);
  float gz = __fadd_rn(dot3(pr[18], pr[19], pr[20], qx, qy, qz), pr[23]);
  int ix = (int)__fdiv_rn(__fsub_rn(gx, -50.0f), 0.5f);
  int iy = (int)__fdiv_rn(__fsub_rn(gy, -50.0f), 0.5f);
  int iz = (int)__fdiv_rn(__fsub_rn(gz, -10.0f), 20.0f);
  if (ix >= 0 && ix < NX && iy >= 0 && iy < NY && iz == 0)
    return (b * NY + iy) * NX + ix;
  return -1;
}

// f64 adjugate inverse -> f32 (used for post_rots; exact for identity).
__device__ inline void inv3x3_f64(const float a_[9], float o[9]) {
  double a[9];
  for (int k = 0; k < 9; ++k) a[k] = (double)a_[k];
  double c00 = a[4] * a[8] - a[5] * a[7];
  double c01 = a[5] * a[6] - a[3] * a[8];
  double c02 = a[3] * a[7] - a[4] * a[6];
  double det = a[0] * c00 + a[1] * c01 + a[2] * c02;
  double id = 1.0 / det;
  o[0] = (float)(c00 * id);
  o[1] = (float)((a[2] * a[7] - a[1] * a[8]) * id);
  o[2] = (float)((a[1] * a[5] - a[2] * a[4]) * id);
  o[3] = (float)(c01 * id);
  o[4] = (float)((a[0] * a[8] - a[2] * a[6]) * id);
  o[5] = (float)((a[2] * a[3] - a[0] * a[5]) * id);
  o[6] = (float)(c02 * id);
  o[7] = (float)((a[1] * a[6] - a[0] * a[7]) * id);
  o[8] = (float)((a[0] * a[4] - a[1] * a[3]) * id);
}

// One thread per (b,n): numpy-exact camera params (LAPACK strti2 inverse of
// the upper-triangular intrinsics; strict no-FMA fp32 matmul). Also zeroes
// the segment counter.
__global__ void setup_kernel(const void* rots, const void* trans,
                             const void* intr, const void* prots,
                             const void* ptrans, float* params) {
  int i = threadIdx.x;
  float probe = ((const float*)intr)[0];  // 500.0 if fp32; denormal if bf16
  int fp32m = (probe > 100.f && probe < 2000.f) ? 1 : 0;
  if (i == 0) {
    ((int*)params)[FLAG_IDX] = fp32m;
    ((int*)params)[CTR_OFF] = 0;
  }
  if (i >= B * N) return;
  float R[9], K[9], PR[9];
  for (int k = 0; k < 9; ++k) {
    R[k] = ldin(rots, (size_t)i * 9 + k, fp32m);
    K[k] = ldin(intr, (size_t)i * 9 + k, fp32m);
    PR[k] = ldin(prots, (size_t)i * 9 + k, fp32m);
  }
  float iPR[9];
  inv3x3_f64(PR, iPR);  // exact identity for this problem
  float i00 = __fdiv_rn(1.f, K[0]);
  float i11 = __fdiv_rn(1.f, K[4]);
  float i22 = __fdiv_rn(1.f, K[8]);
  float i01 = __fmul_rn(-i11, __fmul_rn(i00, K[1]));
  float x1 = __fmul_rn(i00, K[2]);
  x1 = __fadd_rn(x1, __fmul_rn(K[5], i01));
  float x2 = __fmul_rn(i11, K[5]);
  float i02 = __fmul_rn(-i22, x1);
  float i12 = __fmul_rn(-i22, x2);
  float iK[9] = {i00, i01, i02, 0.f, i11, i12, 0.f, 0.f, i22};
  float* o = params + i * PARAMS_PER_CAM;
  for (int k = 0; k < 9; ++k) o[k] = iPR[k];
  for (int k = 0; k < 3; ++k) o[9 + k] = ldin(ptrans, (size_t)i * 3 + k, fp32m);
  for (int r = 0; r < 3; ++r)
    for (int c2 = 0; c2 < 3; ++c2)
      o[12 + r * 3 + c2] = dot3(R[r * 3], R[r * 3 + 1], R[r * 3 + 2], iK[c2],
                                iK[3 + c2], iK[6 + c2]);
  for (int k = 0; k < 3; ++k) o[21 + k] = ldin(trans, (size_t)i * 3 + k, fp32m);
}

__global__ void zero_kernel(float4* __restrict__ acc, int n4) {
  int i = blockIdx.x * blockDim.x + threadIdx.x;
  if (i < n4) acc[i] = make_float4(0.f, 0.f, 0.f, 0.f);
}

// Phase A: one THREAD per (b,n,d,w) group. Run-merge the 16 h's into
// segments (voxel change among kept h's opens a new segment — identical
// grouping/ordering semantics to R3's flush logic). Wave-scan + one
// atomicAdd/wave appends segments (packed int2: (g<<16)|hmask, voxel).
__global__ __launch_bounds__(256) void geom_kernel(float* params) {
  int g = blockIdx.x * blockDim.x + threadIdx.x;
  int lane = threadIdx.x & 63;
  int* counter = (int*)params + CTR_OFF;
  int2* segs = (int2*)((int*)params + SEG_OFF);
  int nseg = 0;
  const float* pr = nullptr;
  float ax = 0.f, az = 0.f;
  int b = 0;
  if (g < NGROUPS) {
    int w = g % FW;
    int t = g / FW;
    int d = t % D;
    t /= D;
    int n = t % N;
    b = t / N;
    pr = params + (b * N + n) * PARAMS_PER_CAM;
    float u = (w == FW - 1) ? 703.0f : (float)((double)w * (703.0 / 43.0));
    float dep = (float)(2 + d);
    ax = __fsub_rn(u, pr[9]);
    az = __fsub_rn(dep, pr[11]);
    int curvox = -1;
    for (int h = 0; h < FH; ++h) {
      int vox = voxel_of(pr, ax, az, b, h);
      if (vox >= 0 && vox != curvox) {
        ++nseg;
        curvox = vox;
      }
    }
  }
  // 64-lane exclusive scan (all lanes participate)
  int incl = nseg;
#pragma unroll
  for (int s = 1; s < 64; s <<= 1) {
    int y = __shfl_up(incl, s, 64);
    if (lane >= s) incl += y;
  }
  int total = __shfl(incl, 63, 64);
  int excl = incl - nseg;
  int basev = 0;
  if (lane == 63 && total > 0) basev = atomicAdd(counter, total);
  basev = __shfl(basev, 63, 64);
  if (g < NGROUPS && nseg > 0) {
    int curvox = -1, mask = 0, k = 0;
    for (int h = 0; h < FH; ++h) {
      int vox = voxel_of(pr, ax, az, b, h);
      if (vox >= 0) {
        if (vox != curvox) {
          if (curvox >= 0) {
            segs[basev + excl + k] = make_int2((g << 16) | mask, curvox);
            ++k;
          }
          curvox = vox;
          mask = 0;
        }
        mask |= (1 << h);
      }
    }
    if (curvox >= 0) segs[basev + excl + k] = make_int2((g << 16) | mask, curvox);
  }
}

// Phase B: one wave per segment (grid-stride). All masked h-loads issue
// independently (16 in flight), left-fold sum in ascending h, single
// coalesced 256 B atomic flush. Pure memory streaming.
__global__ __launch_bounds__(256) void gather_kernel(
    const void* __restrict__ x, const float* __restrict__ params,
    float* __restrict__ acc) {
  int lane = threadIdx.x & 63;
  int wid = blockIdx.x * (blockDim.x >> 6) + (threadIdx.x >> 6);
  int nwaves = gridDim.x * (blockDim.x >> 6);
  int total = ((const int*)params)[CTR_OFF];
  int fp32m = ((const int*)params)[FLAG_IDX];
  const int2* segs = (const int2*)((const int*)params + SEG_OFF);
  for (int s = wid; s < total; s += nwaves) {
    int2 e = segs[s];
    int g = ((unsigned)e.x) >> 16;
    int mask = e.x & 0xffff;
    int vox = e.y;
    int w = g % FW;
    int t = g / FW;  // (b*N+n)*D + d
    size_t base = ((size_t)t * FH * FW + w) * (size_t)C + lane;
    float sum = 0.f;
    int m = mask;
    while (m) {
      int h = __builtin_ctz(m);
      m &= m - 1;
      sum = __fadd_rn(sum, ldin(x, base + (size_t)(h * FW * C), fp32m));
    }
    atomicAdd(acc + (size_t)vox * C + lane, sum);
  }
}

// (B,NY,NX,C) fp32 -> (B,C,NY,NX) out dtype. One block per (b,y) row:
// coalesced float4 reads -> LDS (pad 65) -> coalesced float4 writes.
__global__ __launch_bounds__(256) void finalize_kernel(
    const float* __restrict__ acc, void* __restrict__ out,
    const float* __restrict__ params) {
  int fp32m = ((const int*)params)[FLAG_IDX];
  int y = blockIdx.x % NY;
  int b = blockIdx.x / NY;
  __shared__ float tile[NX * 65];
  const float4* src = (const float4*)(acc + (size_t)(b * NY + y) * NX * C);
  for (int i = threadIdx.x; i < NX * 16; i += 256) {
    float4 vv = src[i];
    int xx = i >> 4, c4 = i & 15;
    float* dst = &tile[xx * 65 + c4 * 4];
    dst[0] = vv.x;
    dst[1] = vv.y;
    dst[2] = vv.z;
    dst[3] = vv.w;
  }
  __syncthreads();
  for (int i = threadIdx.x; i < C * (NX / 4); i += 256) {
    int cc = i / (NX / 4), k = i % (NX / 4);
    int xx = 4 * k;
    float4 vv;
    vv.x = tile[xx * 65 + cc];
    vv.y = tile[(xx + 1) * 65 + cc];
    vv.z = tile[(xx + 2) * 65 + cc];
    vv.w = tile[(xx + 3) * 65 + cc];
    size_t o = ((size_t)(b * C + cc) * NY + y) * NX + xx;
    if (fp32m) {
      *(float4*)((float*)out + o) = vv;
    } else {
      __hip_bfloat16* op = (__hip_bfloat16*)out + o;
      op[0] = __float2bfloat16(vv.x);
      op[1] = __float2bfloat16(vv.y);
      op[2] = __float2bfloat16(vv.z);
      op[3] = __float2bfloat16(vv.w);
    }
  }
}

extern "C" void kernel_launch(void* const* d_in, const int* in_sizes, int n_in,
                              void* d_out, int out_size, void* d_ws,
                              size_t ws_size, hipStream_t stream) {
  const void* x = d_in[0];
  const void* rots = d_in[1];
  const void* trans = d_in[2];
  const void* intr = d_in[3];
  const void* prots = d_in[4];
  const void* ptrans = d_in[5];

  float* acc = (float*)d_ws;        // 10.24M fp32 accumulator
  float* params = acc + ACC_ELEMS;  // 577 fp32 | counter | segment list

  setup_kernel<<<1, 64, 0, stream>>>(rots, trans, intr, prots, ptrans, params);

  int n4 = (int)(ACC_ELEMS / 4);
  zero_kernel<<<(n4 + 255) / 256, 256, 0, stream>>>((float4*)acc, n4);

  geom_kernel<<<(NGROUPS + 255) / 256, 256, 0, stream>>>(params);

  gather_kernel<<<1024, 256, 0, stream>>>(x, params, acc);

  finalize_kernel<<<B * NY, 256, 0, stream>>>(acc, d_out, params);
}

// Round 5
// 310.973 us; speedup vs baseline: 1.1780x; 1.1780x over previous
//
#include <hip/hip_runtime.h>
#include <hip/hip_bf16.h>

namespace {
constexpr int B = 4, N = 6, D = 41, FH = 16, FW = 44, C = 64;
constexpr int NX = 200, NY = 200;                 // NZ = 1
constexpr int NGROUPS = B * N * D * FW;           // 43296 ray-groups (all h)
constexpr long long ACC_ELEMS = (long long)B * NY * NX * C;  // 10,240,000
constexpr int PARAMS_PER_CAM = 24;                // iPR[9], pt[3], M[9], t[3]
constexpr int FLAG_IDX = B * N * PARAMS_PER_CAM;  // int flag at params[576]
// ws float-offsets: [0,ACC) acc | [ACC, ACC+577) params+flag |
// counter int at params[640] | segment list (int2) at params[704]
constexpr int CTR_OFF = 640;
constexpr int SEG_OFF = 704;
}

__device__ __forceinline__ float ldin(const void* p, size_t idx, int fp32m) {
  return fp32m ? ((const float*)p)[idx]
               : __bfloat162float(((const __hip_bfloat16*)p)[idx]);
}

// Strict fp32 left-fold 3-term dot (numpy einsum order, no FMA).
__device__ __forceinline__ float dot3(float m0, float m1, float m2, float a0,
                                      float a1, float a2) {
  return __fadd_rn(__fadd_rn(__fmul_rn(m0, a0), __fmul_rn(m1, a1)),
                   __fmul_rn(m2, a2));
}

// Per-(group,h) voxel id, or -1 if not kept. Bit-identical fp32 ops vs R2/R3.
__device__ __forceinline__ int voxel_of(const float* pr, float ax, float az,
                                        int b, int h) {
  float v = (float)(17 * h);  // linspace(0,255,16), exact
  float ay = __fsub_rn(v, pr[10]);
  float qx = dot3(pr[0], pr[1], pr[2], ax, ay, az);
  float qy = dot3(pr[3], pr[4], pr[5], ax, ay, az);
  float qz = dot3(pr[6], pr[7], pr[8], ax, ay, az);
  qx = __fmul_rn(qx, qz);
  qy = __fmul_rn(qy, qz);
  float gx = __fadd_rn(dot3(pr[12], pr[13], pr[14], qx, qy, qz), pr[21]);
  float gy = __fadd_rn(dot3(pr[15], pr[16], pr[17], qx, qy, qz), pr[22]);
  float gz = __fadd_rn(dot3(pr[18], pr[19], pr[20], qx, qy, qz), pr[23]);
  int ix = (int)__fdiv_rn(__fsub_rn(gx, -50.0f), 0.5f);
  int iy = (int)__fdiv_rn(__fsub_rn(gy, -50.0f), 0.5f);
  int iz = (int)__fdiv_rn(__fsub_rn(gz, -10.0f), 20.0f);
  if (ix >= 0 && ix < NX && iy >= 0 && iy < NY && iz == 0)
    return (b * NY + iy) * NX + ix;
  return -1;
}

// f64 adjugate inverse -> f32 (used for post_rots; exact for identity).
__device__ inline void inv3x3_f64(const float a_[9], float o[9]) {
  double a[9];
  for (int k = 0; k < 9; ++k) a[k] = (double)a_[k];
  double c00 = a[4] * a[8] - a[5] * a[7];
  double c01 = a[5] * a[6] - a[3] * a[8];
  double c02 = a[3] * a[7] - a[4] * a[6];
  double det = a[0] * c00 + a[1] * c01 + a[2] * c02;
  double id = 1.0 / det;
  o[0] = (float)(c00 * id);
  o[1] = (float)((a[2] * a[7] - a[1] * a[8]) * id);
  o[2] = (float)((a[1] * a[5] - a[2] * a[4]) * id);
  o[3] = (float)(c01 * id);
  o[4] = (float)((a[0] * a[8] - a[2] * a[6]) * id);
  o[5] = (float)((a[2] * a[3] - a[0] * a[5]) * id);
  o[6] = (float)(c02 * id);
  o[7] = (float)((a[1] * a[6] - a[0] * a[7]) * id);
  o[8] = (float)((a[0] * a[4] - a[1] * a[3]) * id);
}

// One thread per (b,n): numpy-exact camera params (LAPACK strti2 inverse of
// the upper-triangular intrinsics; strict no-FMA fp32 matmul). Also zeroes
// the segment counter.
__global__ void setup_kernel(const void* rots, const void* trans,
                             const void* intr, const void* prots,
                             const void* ptrans, float* params) {
  int i = threadIdx.x;
  float probe = ((const float*)intr)[0];  // 500.0 if fp32; denormal if bf16
  int fp32m = (probe > 100.f && probe < 2000.f) ? 1 : 0;
  if (i == 0) {
    ((int*)params)[FLAG_IDX] = fp32m;
    ((int*)params)[CTR_OFF] = 0;
  }
  if (i >= B * N) return;
  float R[9], K[9], PR[9];
  for (int k = 0; k < 9; ++k) {
    R[k] = ldin(rots, (size_t)i * 9 + k, fp32m);
    K[k] = ldin(intr, (size_t)i * 9 + k, fp32m);
    PR[k] = ldin(prots, (size_t)i * 9 + k, fp32m);
  }
  float iPR[9];
  inv3x3_f64(PR, iPR);  // exact identity for this problem
  float i00 = __fdiv_rn(1.f, K[0]);
  float i11 = __fdiv_rn(1.f, K[4]);
  float i22 = __fdiv_rn(1.f, K[8]);
  float i01 = __fmul_rn(-i11, __fmul_rn(i00, K[1]));
  float x1 = __fmul_rn(i00, K[2]);
  x1 = __fadd_rn(x1, __fmul_rn(K[5], i01));
  float x2 = __fmul_rn(i11, K[5]);
  float i02 = __fmul_rn(-i22, x1);
  float i12 = __fmul_rn(-i22, x2);
  float iK[9] = {i00, i01, i02, 0.f, i11, i12, 0.f, 0.f, i22};
  float* o = params + i * PARAMS_PER_CAM;
  for (int k = 0; k < 9; ++k) o[k] = iPR[k];
  for (int k = 0; k < 3; ++k) o[9 + k] = ldin(ptrans, (size_t)i * 3 + k, fp32m);
  for (int r = 0; r < 3; ++r)
    for (int c2 = 0; c2 < 3; ++c2)
      o[12 + r * 3 + c2] = dot3(R[r * 3], R[r * 3 + 1], R[r * 3 + 2], iK[c2],
                                iK[3 + c2], iK[6 + c2]);
  for (int k = 0; k < 3; ++k) o[21 + k] = ldin(trans, (size_t)i * 3 + k, fp32m);
}

__global__ void zero_kernel(float4* __restrict__ acc, int n4) {
  int i = blockIdx.x * blockDim.x + threadIdx.x;
  if (i < n4) acc[i] = make_float4(0.f, 0.f, 0.f, 0.f);
}

// Phase A: one THREAD per (b,n,d,w) group. Run-merge the 16 h's into
// segments (voxel change among kept h's opens a new segment — identical
// grouping semantics to R3's flush logic). Wave-scan + one atomicAdd/wave
// appends segments (packed int2: (g<<16)|hmask, voxel).
__global__ __launch_bounds__(256) void geom_kernel(float* params) {
  int g = blockIdx.x * blockDim.x + threadIdx.x;
  int lane = threadIdx.x & 63;
  int* counter = (int*)params + CTR_OFF;
  int2* segs = (int2*)((int*)params + SEG_OFF);
  int nseg = 0;
  const float* pr = nullptr;
  float ax = 0.f, az = 0.f;
  int b = 0;
  if (g < NGROUPS) {
    int w = g % FW;
    int t = g / FW;
    int d = t % D;
    t /= D;
    int n = t % N;
    b = t / N;
    pr = params + (b * N + n) * PARAMS_PER_CAM;
    float u = (w == FW - 1) ? 703.0f : (float)((double)w * (703.0 / 43.0));
    float dep = (float)(2 + d);
    ax = __fsub_rn(u, pr[9]);
    az = __fsub_rn(dep, pr[11]);
    int curvox = -1;
    for (int h = 0; h < FH; ++h) {
      int vox = voxel_of(pr, ax, az, b, h);
      if (vox >= 0 && vox != curvox) {
        ++nseg;
        curvox = vox;
      }
    }
  }
  // 64-lane exclusive scan (all lanes participate)
  int incl = nseg;
#pragma unroll
  for (int s = 1; s < 64; s <<= 1) {
    int y = __shfl_up(incl, s, 64);
    if (lane >= s) incl += y;
  }
  int total = __shfl(incl, 63, 64);
  int excl = incl - nseg;
  int basev = 0;
  if (lane == 63 && total > 0) basev = atomicAdd(counter, total);
  basev = __shfl(basev, 63, 64);
  if (g < NGROUPS && nseg > 0) {
    int curvox = -1, mask = 0, k = 0;
    for (int h = 0; h < FH; ++h) {
      int vox = voxel_of(pr, ax, az, b, h);
      if (vox >= 0) {
        if (vox != curvox) {
          if (curvox >= 0) {
            segs[basev + excl + k] = make_int2((g << 16) | mask, curvox);
            ++k;
          }
          curvox = vox;
          mask = 0;
        }
        mask |= (1 << h);
      }
    }
    if (curvox >= 0)
      segs[basev + excl + k] = make_int2((g << 16) | mask, curvox);
  }
}

// Phase B: ONE segment per wave (65536 waves; grid-stride only as overflow
// guard). Fixed fully-unrolled h loop: predicated loads into a 16-register
// array (mask is wave-uniform -> scalar branch; taken loads all issue
// independently, 16 requests in flight), then a single fold + one coalesced
// 256 B atomic flush. +0.0f folds for untaken h are fp32 rounding no-ops.
__global__ __launch_bounds__(256) void gather_kernel(
    const void* __restrict__ x, const float* __restrict__ params,
    float* __restrict__ acc) {
  int lane = threadIdx.x & 63;
  int wid = blockIdx.x * (blockDim.x >> 6) + (threadIdx.x >> 6);
  int nwaves = gridDim.x * (blockDim.x >> 6);
  int total = ((const int*)params)[CTR_OFF];
  int fp32m = ((const int*)params)[FLAG_IDX];
  const int2* segs = (const int2*)((const int*)params + SEG_OFF);
  for (int s = wid; s < total; s += nwaves) {
    int2 e = segs[s];
    int g = ((unsigned)e.x) >> 16;
    int mask = e.x & 0xffff;
    int vox = e.y;
    int w = g % FW;
    int t = g / FW;  // (b*N+n)*D + d
    size_t base = ((size_t)t * FH * FW + w) * (size_t)C + lane;
    float v[FH];
#pragma unroll
    for (int h = 0; h < FH; ++h)
      v[h] = ((mask >> h) & 1) ? ldin(x, base + (size_t)(h * FW * C), fp32m)
                               : 0.0f;
    float sum = v[0];
#pragma unroll
    for (int h = 1; h < FH; ++h) sum = __fadd_rn(sum, v[h]);
    atomicAdd(acc + (size_t)vox * C + lane, sum);
  }
}

// (B,NY,NX,C) fp32 -> (B,C,NY,NX) out dtype. One block per (b,y) row:
// coalesced float4 reads -> LDS (pad 65) -> coalesced float4 writes.
__global__ __launch_bounds__(256) void finalize_kernel(
    const float* __restrict__ acc, void* __restrict__ out,
    const float* __restrict__ params) {
  int fp32m = ((const int*)params)[FLAG_IDX];
  int y = blockIdx.x % NY;
  int b = blockIdx.x / NY;
  __shared__ float tile[NX * 65];
  const float4* src = (const float4*)(acc + (size_t)(b * NY + y) * NX * C);
  for (int i = threadIdx.x; i < NX * 16; i += 256) {
    float4 vv = src[i];
    int xx = i >> 4, c4 = i & 15;
    float* dst = &tile[xx * 65 + c4 * 4];
    dst[0] = vv.x;
    dst[1] = vv.y;
    dst[2] = vv.z;
    dst[3] = vv.w;
  }
  __syncthreads();
  for (int i = threadIdx.x; i < C * (NX / 4); i += 256) {
    int cc = i / (NX / 4), k = i % (NX / 4);
    int xx = 4 * k;
    float4 vv;
    vv.x = tile[xx * 65 + cc];
    vv.y = tile[(xx + 1) * 65 + cc];
    vv.z = tile[(xx + 2) * 65 + cc];
    vv.w = tile[(xx + 3) * 65 + cc];
    size_t o = ((size_t)(b * C + cc) * NY + y) * NX + xx;
    if (fp32m) {
      *(float4*)((float*)out + o) = vv;
    } else {
      __hip_bfloat16* op = (__hip_bfloat16*)out + o;
      op[0] = __float2bfloat16(vv.x);
      op[1] = __float2bfloat16(vv.y);
      op[2] = __float2bfloat16(vv.z);
      op[3] = __float2bfloat16(vv.w);
    }
  }
}

extern "C" void kernel_launch(void* const* d_in, const int* in_sizes, int n_in,
                              void* d_out, int out_size, void* d_ws,
                              size_t ws_size, hipStream_t stream) {
  const void* x = d_in[0];
  const void* rots = d_in[1];
  const void* trans = d_in[2];
  const void* intr = d_in[3];
  const void* prots = d_in[4];
  const void* ptrans = d_in[5];

  float* acc = (float*)d_ws;        // 10.24M fp32 accumulator
  float* params = acc + ACC_ELEMS;  // 577 fp32 | counter | segment list

  setup_kernel<<<1, 64, 0, stream>>>(rots, trans, intr, prots, ptrans, params);

  int n4 = (int)(ACC_ELEMS / 4);
  zero_kernel<<<(n4 + 255) / 256, 256, 0, stream>>>((float4*)acc, n4);

  geom_kernel<<<(NGROUPS + 255) / 256, 256, 0, stream>>>(params);

  // 16384 blocks x 4 waves = 65536 waves -> one segment per wave (~42K segs)
  gather_kernel<<<16384, 256, 0, stream>>>(x, params, acc);

  finalize_kernel<<<B * NY, 256, 0, stream>>>(acc, d_out, params);
}

// Round 6
// 302.738 us; speedup vs baseline: 1.2101x; 1.0272x over previous
//
#include <hip/hip_runtime.h>
#include <hip/hip_bf16.h>

namespace {
constexpr int B = 4, N = 6, D = 41, FH = 16, FW = 44, C = 64;
constexpr int NX = 200, NY = 200;                 // NZ = 1
constexpr int NGROUPS = B * N * D * FW;           // 43296 ray-groups (all h)
constexpr long long ACC_ELEMS = (long long)B * NY * NX * C;  // 10,240,000
constexpr int NVOX = B * NY * NX;                 // 160,000
constexpr int PARAMS_PER_CAM = 24;                // iPR[9], pt[3], M[9], t[3]
// ws byte layout:
//   [0, 40,960,000)            fp32 acc (B,NY,NX,C)
//   [40,960,000, +4)           segment counter (int)
//   [40,960,004, +160,000)     per-voxel touched flags (bytes)
//   [41,120,008, ...)          segment list (int2)
constexpr size_t CTR_BYTE = (size_t)ACC_ELEMS * 4;          // 40,960,000
constexpr size_t FLAG_BYTE = CTR_BYTE + 4;
constexpr size_t SEG_BYTE = 41120008;                       // 8-aligned
constexpr int ZINIT_DWORDS = (4 + NVOX + 3) / 4;            // ctr + flags
}

__device__ __forceinline__ float ldin(const void* p, size_t idx, int fp32m) {
  return fp32m ? ((const float*)p)[idx]
               : __bfloat162float(((const __hip_bfloat16*)p)[idx]);
}

__device__ __forceinline__ int probe_fp32(const void* intr) {
  float probe = ((const float*)intr)[0];  // 500.0 if fp32; denormal if bf16
  return (probe > 100.f && probe < 2000.f) ? 1 : 0;
}

// Strict fp32 left-fold 3-term dot (numpy einsum order, no FMA).
__device__ __forceinline__ float dot3(float m0, float m1, float m2, float a0,
                                      float a1, float a2) {
  return __fadd_rn(__fadd_rn(__fmul_rn(m0, a0), __fmul_rn(m1, a1)),
                   __fmul_rn(m2, a2));
}

// Per-(group,h) voxel id, or -1 if not kept. Bit-identical fp32 ops vs R2-R5.
__device__ __forceinline__ int voxel_of(const float* pr, float ax, float az,
                                        int b, int h) {
  float v = (float)(17 * h);  // linspace(0,255,16), exact
  float ay = __fsub_rn(v, pr[10]);
  float qx = dot3(pr[0], pr[1], pr[2], ax, ay, az);
  float qy = dot3(pr[3], pr[4], pr[5], ax, ay, az);
  float qz = dot3(pr[6], pr[7], pr[8], ax, ay, az);
  qx = __fmul_rn(qx, qz);
  qy = __fmul_rn(qy, qz);
  float gx = __fadd_rn(dot3(pr[12], pr[13], pr[14], qx, qy, qz), pr[21]);
  float gy = __fadd_rn(dot3(pr[15], pr[16], pr[17], qx, qy, qz), pr[22]);
  float gz = __fadd_rn(dot3(pr[18], pr[19], pr[20], qx, qy, qz), pr[23]);
  int ix = (int)__fdiv_rn(__fsub_rn(gx, -50.0f), 0.5f);
  int iy = (int)__fdiv_rn(__fsub_rn(gy, -50.0f), 0.5f);
  int iz = (int)__fdiv_rn(__fsub_rn(gz, -10.0f), 20.0f);
  if (ix >= 0 && ix < NX && iy >= 0 && iy < NY && iz == 0)
    return (b * NY + iy) * NX + ix;
  return -1;
}

// f64 adjugate inverse -> f32 (used for post_rots; exact for identity).
__device__ inline void inv3x3_f64(const float a_[9], float o[9]) {
  double a[9];
  for (int k = 0; k < 9; ++k) a[k] = (double)a_[k];
  double c00 = a[4] * a[8] - a[5] * a[7];
  double c01 = a[5] * a[6] - a[3] * a[8];
  double c02 = a[3] * a[7] - a[4] * a[6];
  double det = a[0] * c00 + a[1] * c01 + a[2] * c02;
  double id = 1.0 / det;
  o[0] = (float)(c00 * id);
  o[1] = (float)((a[2] * a[7] - a[1] * a[8]) * id);
  o[2] = (float)((a[1] * a[5] - a[2] * a[4]) * id);
  o[3] = (float)(c01 * id);
  o[4] = (float)((a[0] * a[8] - a[2] * a[6]) * id);
  o[5] = (float)((a[2] * a[3] - a[0] * a[5]) * id);
  o[6] = (float)(c02 * id);
  o[7] = (float)((a[1] * a[6] - a[0] * a[7]) * id);
  o[8] = (float)((a[0] * a[4] - a[1] * a[3]) * id);
}

// numpy-exact per-camera params (LAPACK strti2 inverse of the upper-
// triangular intrinsics; strict no-FMA fp32 matmul). One call per camera.
__device__ void compute_cam_params(int i, const void* rots, const void* trans,
                                   const void* intr, const void* prots,
                                   const void* ptrans, int fp32m, float* o) {
  float R[9], K[9], PR[9];
  for (int k = 0; k < 9; ++k) {
    R[k] = ldin(rots, (size_t)i * 9 + k, fp32m);
    K[k] = ldin(intr, (size_t)i * 9 + k, fp32m);
    PR[k] = ldin(prots, (size_t)i * 9 + k, fp32m);
  }
  float iPR[9];
  inv3x3_f64(PR, iPR);  // exact identity for this problem
  float i00 = __fdiv_rn(1.f, K[0]);
  float i11 = __fdiv_rn(1.f, K[4]);
  float i22 = __fdiv_rn(1.f, K[8]);
  float i01 = __fmul_rn(-i11, __fmul_rn(i00, K[1]));
  float x1 = __fmul_rn(i00, K[2]);
  x1 = __fadd_rn(x1, __fmul_rn(K[5], i01));
  float x2 = __fmul_rn(i11, K[5]);
  float i02 = __fmul_rn(-i22, x1);
  float i12 = __fmul_rn(-i22, x2);
  float iK[9] = {i00, i01, i02, 0.f, i11, i12, 0.f, 0.f, i22};
  for (int k = 0; k < 9; ++k) o[k] = iPR[k];
  for (int k = 0; k < 3; ++k) o[9 + k] = ldin(ptrans, (size_t)i * 3 + k, fp32m);
  for (int r = 0; r < 3; ++r)
    for (int c2 = 0; c2 < 3; ++c2)
      o[12 + r * 3 + c2] = dot3(R[r * 3], R[r * 3 + 1], R[r * 3 + 2], iK[c2],
                                iK[3 + c2], iK[6 + c2]);
  for (int k = 0; k < 3; ++k) o[21 + k] = ldin(trans, (size_t)i * 3 + k, fp32m);
}

// Zero the segment counter + voxel flags (160,004 bytes).
__global__ void zinit_kernel(char* __restrict__ ws) {
  int i = blockIdx.x * blockDim.x + threadIdx.x;
  if (i < ZINIT_DWORDS) ((int*)(ws + CTR_BYTE))[i] = 0;
}

// Phase A: one THREAD per (b,n,d,w) group. Camera params recomputed per
// block in LDS (bit-identical -> identical segments in every block).
// Run-merge the 16 h's into segments; wave-scan + one atomicAdd/wave
// appends (packed int2: (g<<16)|hmask, voxel).
__global__ __launch_bounds__(256) void geom_kernel(const void* rots,
                                                   const void* trans,
                                                   const void* intr,
                                                   const void* prots,
                                                   const void* ptrans,
                                                   char* __restrict__ ws) {
  __shared__ float sp[B * N * PARAMS_PER_CAM];
  int fp32m = probe_fp32(intr);
  if (threadIdx.x < B * N)
    compute_cam_params(threadIdx.x, rots, trans, intr, prots, ptrans, fp32m,
                       sp + threadIdx.x * PARAMS_PER_CAM);
  __syncthreads();
  int g = blockIdx.x * blockDim.x + threadIdx.x;
  int lane = threadIdx.x & 63;
  int* counter = (int*)(ws + CTR_BYTE);
  int2* segs = (int2*)(ws + SEG_BYTE);
  int nseg = 0;
  const float* pr = nullptr;
  float ax = 0.f, az = 0.f;
  int b = 0;
  if (g < NGROUPS) {
    int w = g % FW;
    int t = g / FW;
    int d = t % D;
    t /= D;
    int n = t % N;
    b = t / N;
    pr = sp + (b * N + n) * PARAMS_PER_CAM;
    float u = (w == FW - 1) ? 703.0f : (float)((double)w * (703.0 / 43.0));
    float dep = (float)(2 + d);
    ax = __fsub_rn(u, pr[9]);
    az = __fsub_rn(dep, pr[11]);
    int curvox = -1;
    for (int h = 0; h < FH; ++h) {
      int vox = voxel_of(pr, ax, az, b, h);
      if (vox >= 0 && vox != curvox) {
        ++nseg;
        curvox = vox;
      }
    }
  }
  // 64-lane exclusive scan (all lanes participate)
  int incl = nseg;
#pragma unroll
  for (int s = 1; s < 64; s <<= 1) {
    int y = __shfl_up(incl, s, 64);
    if (lane >= s) incl += y;
  }
  int total = __shfl(incl, 63, 64);
  int excl = incl - nseg;
  int basev = 0;
  if (lane == 63 && total > 0) basev = atomicAdd(counter, total);
  basev = __shfl(basev, 63, 64);
  if (g < NGROUPS && nseg > 0) {
    int curvox = -1, mask = 0, k = 0;
    for (int h = 0; h < FH; ++h) {
      int vox = voxel_of(pr, ax, az, b, h);
      if (vox >= 0) {
        if (vox != curvox) {
          if (curvox >= 0) {
            segs[basev + excl + k] = make_int2((g << 16) | mask, curvox);
            ++k;
          }
          curvox = vox;
          mask = 0;
        }
        mask |= (1 << h);
      }
    }
    if (curvox >= 0)
      segs[basev + excl + k] = make_int2((g << 16) | mask, curvox);
  }
}

// Zero only the touched acc chunks + set flags. One wave per segment;
// duplicate voxels across waves all write 0 (idempotent). Runs before
// gather (stream order).
__global__ __launch_bounds__(256) void zseg_kernel(char* __restrict__ ws) {
  int lane = threadIdx.x & 63;
  int wid = blockIdx.x * (blockDim.x >> 6) + (threadIdx.x >> 6);
  int nwaves = gridDim.x * (blockDim.x >> 6);
  int total = *(const int*)(ws + CTR_BYTE);
  const int2* segs = (const int2*)(ws + SEG_BYTE);
  float* acc = (float*)ws;
  unsigned char* flags = (unsigned char*)(ws + FLAG_BYTE);
  for (int s = wid; s < total; s += nwaves) {
    int vox = segs[s].y;
    acc[(size_t)vox * C + lane] = 0.0f;
    if (lane == 0) flags[vox] = 1;
  }
}

// Phase B: ONE segment per wave. Fully-unrolled predicated h-loads (mask is
// wave-uniform; taken loads all in flight), single fold, one coalesced
// 256 B atomic flush.
__global__ __launch_bounds__(256) void gather_kernel(const void* __restrict__ x,
                                                     const void* intr,
                                                     char* __restrict__ ws) {
  int lane = threadIdx.x & 63;
  int wid = blockIdx.x * (blockDim.x >> 6) + (threadIdx.x >> 6);
  int nwaves = gridDim.x * (blockDim.x >> 6);
  int total = *(const int*)(ws + CTR_BYTE);
  int fp32m = probe_fp32(intr);
  const int2* segs = (const int2*)(ws + SEG_BYTE);
  float* acc = (float*)ws;
  for (int s = wid; s < total; s += nwaves) {
    int2 e = segs[s];
    int g = ((unsigned)e.x) >> 16;
    int mask = e.x & 0xffff;
    int vox = e.y;
    int w = g % FW;
    int t = g / FW;  // (b*N+n)*D + d
    size_t base = ((size_t)t * FH * FW + w) * (size_t)C + lane;
    float v[FH];
#pragma unroll
    for (int h = 0; h < FH; ++h)
      v[h] = ((mask >> h) & 1) ? ldin(x, base + (size_t)(h * FW * C), fp32m)
                               : 0.0f;
    float sum = v[0];
#pragma unroll
    for (int h = 1; h < FH; ++h) sum = __fadd_rn(sum, v[h]);
    atomicAdd(acc + (size_t)vox * C + lane, sum);
  }
}

// (B,NY,NX,C) fp32 -> (B,C,NY,NX) out dtype. One block per (b,y) row.
// Untouched voxels (flag==0) produce 0.0 without reading acc.
__global__ __launch_bounds__(256) void finalize_kernel(
    const char* __restrict__ ws, void* __restrict__ out, const void* intr) {
  int fp32m = probe_fp32(intr);
  int y = blockIdx.x % NY;
  int b = blockIdx.x / NY;
  const float* acc = (const float*)ws;
  const unsigned char* flg =
      (const unsigned char*)(ws + FLAG_BYTE) + (size_t)(b * NY + y) * NX;
  __shared__ float tile[NX * 65];
  const float4* src = (const float4*)(acc + (size_t)(b * NY + y) * NX * C);
  for (int i = threadIdx.x; i < NX * 16; i += 256) {
    int xx = i >> 4, c4 = i & 15;
    float4 vv = flg[xx] ? src[i] : make_float4(0.f, 0.f, 0.f, 0.f);
    float* dst = &tile[xx * 65 + c4 * 4];
    dst[0] = vv.x;
    dst[1] = vv.y;
    dst[2] = vv.z;
    dst[3] = vv.w;
  }
  __syncthreads();
  for (int i = threadIdx.x; i < C * (NX / 4); i += 256) {
    int cc = i / (NX / 4), k = i % (NX / 4);
    int xx = 4 * k;
    float4 vv;
    vv.x = tile[xx * 65 + cc];
    vv.y = tile[(xx + 1) * 65 + cc];
    vv.z = tile[(xx + 2) * 65 + cc];
    vv.w = tile[(xx + 3) * 65 + cc];
    size_t o = ((size_t)(b * C + cc) * NY + y) * NX + xx;
    if (fp32m) {
      *(float4*)((float*)out + o) = vv;
    } else {
      __hip_bfloat16* op = (__hip_bfloat16*)out + o;
      op[0] = __float2bfloat16(vv.x);
      op[1] = __float2bfloat16(vv.y);
      op[2] = __float2bfloat16(vv.z);
      op[3] = __float2bfloat16(vv.w);
    }
  }
}

extern "C" void kernel_launch(void* const* d_in, const int* in_sizes, int n_in,
                              void* d_out, int out_size, void* d_ws,
                              size_t ws_size, hipStream_t stream) {
  const void* x = d_in[0];
  const void* rots = d_in[1];
  const void* trans = d_in[2];
  const void* intr = d_in[3];
  const void* prots = d_in[4];
  const void* ptrans = d_in[5];
  char* ws = (char*)d_ws;

  zinit_kernel<<<(ZINIT_DWORDS + 255) / 256, 256, 0, stream>>>(ws);

  geom_kernel<<<(NGROUPS + 255) / 256, 256, 0, stream>>>(rots, trans, intr,
                                                         prots, ptrans, ws);

  // ~42K segments; 16384 blocks x 4 waves = 65536 waves, one segment each
  zseg_kernel<<<4096, 256, 0, stream>>>(ws);

  gather_kernel<<<16384, 256, 0, stream>>>(x, intr, ws);

  finalize_kernel<<<B * NY, 256, 0, stream>>>(ws, d_out, intr);
}